// Round 6
// baseline (1059.031 us; speedup 1.0000x reference)
//
#include <hip/hip_runtime.h>
#include <stdint.h>

#define NN 128
#define BB 4096
#define HH 32

typedef float f4 __attribute__((ext_vector_type(4)));

// Pre-pass: bit-pack A transposed. bit d of word (b,node) = (A[b][d][node] != 0).
__global__ __launch_bounds__(256) void pack_bits(const float* __restrict__ A,
                                                 ulonglong2* __restrict__ bitsT) {
    const int tid = blockIdx.x * 256 + threadIdx.x;   // BB*32 threads total
    const int b   = tid >> 5;
    const int ng  = (tid & 31) << 2;                  // this thread's 4 nodes
    const float* Ab = A + (size_t)b * (NN * NN) + ng;
    unsigned long long w0[4] = {0ull, 0ull, 0ull, 0ull};
    unsigned long long w1[4] = {0ull, 0ull, 0ull, 0ull};
#pragma unroll 8
    for (int d = 0; d < 64; ++d) {
        f4 v = __builtin_nontemporal_load((const f4*)(Ab + (size_t)d * NN));
        const unsigned long long bit = 1ull << d;
        if (v[0] != 0.f) w0[0] |= bit;
        if (v[1] != 0.f) w0[1] |= bit;
        if (v[2] != 0.f) w0[2] |= bit;
        if (v[3] != 0.f) w0[3] |= bit;
    }
#pragma unroll 8
    for (int d = 0; d < 64; ++d) {
        f4 v = __builtin_nontemporal_load((const f4*)(Ab + (size_t)(d + 64) * NN));
        const unsigned long long bit = 1ull << d;
        if (v[0] != 0.f) w1[0] |= bit;
        if (v[1] != 0.f) w1[1] |= bit;
        if (v[2] != 0.f) w1[2] |= bit;
        if (v[3] != 0.f) w1[3] |= bit;
    }
    ulonglong2* o = bitsT + b * NN + ng;
#pragma unroll
    for (int i = 0; i < 4; ++i) {
        ulonglong2 r; r.x = w0[i]; r.y = w1[i];
        o[i] = r;
    }
}

__device__ __forceinline__ int mbcnt64(unsigned long long m) {
    return __builtin_amdgcn_mbcnt_hi((unsigned int)(m >> 32),
           __builtin_amdgcn_mbcnt_lo((unsigned int)m, 0));
}
__device__ __forceinline__ unsigned long long rfl64(unsigned long long v) {
    unsigned int lo = __builtin_amdgcn_readfirstlane((unsigned int)v);
    unsigned int hi = __builtin_amdgcn_readfirstlane((unsigned int)(v >> 32));
    return ((unsigned long long)hi << 32) | lo;
}

// v7 = v6 pipeline + issue-count cuts:
//  (a) gather split into 4 SGPR-uniform-predicated 8-entry sub-blocks
//      (avg cnt~19 -> ~2.5 blocks issued instead of always 4; s_cbranch,
//       no divergence, static unrolling preserved within each block)
//  (b) ent stores BYTE offset of the W1 row (d<<7); node base is an SGPR
//      pointer (node is readfirstlane'd) -> W address = 1 v_add, saddr form.
// Entry regs (value,byteoff) double-buffered across the one-step pipeline
// exactly as v6: W rows for step T load at step TOP from register-resident
// offsets; compaction for T+1 built from state <= T-1 (fresh-path covers
// node_T's contribution, HW-validated r4/r5).
#define STEP(T, ECUR, ENXT, BCUR, BNXT)                                      \
  {                                                                          \
    const char* WnB = (const char*)(W1 + (size_t)node0 * ((NN + 1) * HH));   \
    /* 0: W loads for THIS step (byte offsets already in regs) */            \
    float wv[16];                                                            \
    if (nb_c > 0) { _Pragma("unroll") for (int i = 0; i < 4; ++i) {          \
        int off = __float_as_int(ECUR[i].y) + j4; __builtin_assume(off>=0);  \
        wv[i] = *(const float*)(WnB + off); } }                              \
    if (nb_c > 1) { _Pragma("unroll") for (int i = 4; i < 8; ++i) {          \
        int off = __float_as_int(ECUR[i].y) + j4; __builtin_assume(off>=0);  \
        wv[i] = *(const float*)(WnB + off); } }                              \
    if (nb_c > 2) { _Pragma("unroll") for (int i = 8; i < 12; ++i) {         \
        int off = __float_as_int(ECUR[i].y) + j4; __builtin_assume(off>=0);  \
        wv[i] = *(const float*)(WnB + off); } }                              \
    if (nb_c > 3) { _Pragma("unroll") for (int i = 12; i < 16; ++i) {        \
        int off = __float_as_int(ECUR[i].y) + j4; __builtin_assume(off>=0);  \
        wv[i] = *(const float*)(WnB + off); } }                              \
    /* 1: apply pending update from step T-1 */                              \
    if ((T) > 0) {                                                           \
        if (dob != pend_node && lane == (pend_node & 63)) {                  \
            if (pend_node < 64) out0 = pend_val; else out1 = pend_val;       \
        }                                                                    \
        if (pend_node < 64) nz0 |= 1ull << pend_node;                        \
        else                nz1 |= 1ull << (pend_node - 64);                 \
    }                                                                        \
    /* 2: masks for step T+1 (node_T not yet in nz -> excluded) */           \
    const unsigned long long bw0n = rfl64(vbn.x);                            \
    const unsigned long long bw1n = rfl64(vbn.y);                            \
    const unsigned long long m0 = nz0 & bw0n;                                \
    const unsigned long long m1 = nz1 & bw1n;                                \
    const int c0n  = __popcll(m0);                                           \
    const int cntn = c0n + __popcll(m1);                                     \
    const int cnt4n = (cntn + 3) & ~3;                                       \
    const int nbn = (cntn >= 32) ? 4 : ((cntn + 7) >> 3);                    \
    /* 3: write compaction for T+1 into the other buffer */                  \
    {                                                                        \
        const int p0 = mbcnt64(m0);                                          \
        if (m0 & lanebit) entb[BNXT][p0] = make_float2(out0, fidx0);         \
        const int p1 = c0n + mbcnt64(m1);                                    \
        if (m1 & lanebit) entb[BNXT][p1] = make_float2(out1, fidx1);         \
        const int top = (nbn * 8 > cnt4n) ? nbn * 8 : cnt4n;                 \
        const int pp = cntn + lane;                                          \
        if (pp < top) entb[BNXT][pp] = make_float2(0.f, __int_as_float(0));  \
    }                                                                        \
    asm volatile("s_waitcnt lgkmcnt(0)" ::: "memory");                       \
    /* 4: entry ds_reads for T+1 (consumed next step; predicated) */         \
    if (nbn > 0) { _Pragma("unroll") for (int i = 0; i < 4; ++i)             \
        ENXT[i] = entb[BNXT][2 * i + half]; }                                \
    if (nbn > 1) { _Pragma("unroll") for (int i = 4; i < 8; ++i)             \
        ENXT[i] = entb[BNXT][2 * i + half]; }                                \
    if (nbn > 2) { _Pragma("unroll") for (int i = 8; i < 12; ++i)            \
        ENXT[i] = entb[BNXT][2 * i + half]; }                                \
    if (nbn > 3) { _Pragma("unroll") for (int i = 12; i < 16; ++i)           \
        ENXT[i] = entb[BNXT][2 * i + half]; }                                \
    /* 5: prefetch node_{T+2}, its bits, and T+1's epilogue scalars */       \
    const int node2 = ((T) + 2 < NN)                                         \
        ? __builtin_amdgcn_readfirstlane(ord[(T) + 2]) : 0;                  \
    const ulonglong2 vb2 = bb[node2];                                        \
    const float* Wn_nxt = W1 + (size_t)node1 * ((NN + 1) * HH);              \
    const float w2v_n  = W2[node1 * HH + j];                                 \
    const float b1v_n  = b1[node1 * HH + j];                                 \
    const float xv_n   = x[b * NN + node1];                                  \
    const float b2v_n  = b2[node1];                                          \
    const float w1xv_n = Wn_nxt[NN * HH + j];                                \
    const float wfr_n  = Wn_nxt[(node0 << 5) + j];                           \
    /* 6: FMAs for step T (entries + weights all in regs; predicated) */     \
    float a0 = 0.f, a1 = 0.f, a2 = 0.f, a3 = 0.f;                            \
    if (nb_c > 0) { a0 += ECUR[0].x * wv[0];  a1 += ECUR[1].x * wv[1];       \
                    a2 += ECUR[2].x * wv[2];  a3 += ECUR[3].x * wv[3]; }     \
    if (nb_c > 1) { a0 += ECUR[4].x * wv[4];  a1 += ECUR[5].x * wv[5];       \
                    a2 += ECUR[6].x * wv[6];  a3 += ECUR[7].x * wv[7]; }     \
    if (nb_c > 2) { a0 += ECUR[8].x * wv[8];  a1 += ECUR[9].x * wv[9];       \
                    a2 += ECUR[10].x * wv[10]; a3 += ECUR[11].x * wv[11]; }  \
    if (nb_c > 3) { a0 += ECUR[12].x * wv[12]; a1 += ECUR[13].x * wv[13];    \
                    a2 += ECUR[14].x * wv[14]; a3 += ECUR[15].x * wv[15]; }  \
    float acc = (a0 + a1) + (a2 + a3);                                       \
    /* 7: overflow entries 32..cnt4 (late steps only, in-step chain) */      \
    if (cnt4_c > 32) {                                                       \
        for (int k = 32; k < cnt4_c; k += 4) {                               \
            float2 ea = entb[BCUR][k + half];                                \
            float2 eb = entb[BCUR][k + 2 + half];                            \
            acc += *(const float*)(WnB + (__float_as_int(ea.y) + j4)) * ea.x;\
            acc += *(const float*)(WnB + (__float_as_int(eb.y) + j4)) * eb.x;\
        }                                                                    \
    }                                                                        \
    /* 8: finish step T */                                                   \
    float accT = acc + __shfl_xor(acc, 32);                                  \
    const bool fc = ((T) > 0) && (dob != pend_node) &&                       \
        ((((pend_node < 64) ? (bw0c >> pend_node)                            \
                            : (bw1c >> (pend_node - 64)))) & 1ull);          \
    accT += (fc ? pend_val : 0.f) * wfr;                                     \
    accT += xv * w1xv;                                                       \
    accT += b1v;                                                             \
    const float hv = (accT > 0.f) ? accT : 0.01f * accT;                     \
    float pr = hv * w2v;                                                     \
    pr += __int_as_float(__builtin_amdgcn_update_dpp(                        \
             0, __float_as_int(pr), 0xB1, 0xF, 0xF, true));                  \
    pr += __int_as_float(__builtin_amdgcn_update_dpp(                        \
             0, __float_as_int(pr), 0x4E, 0xF, 0xF, true));                  \
    pr += __int_as_float(__builtin_amdgcn_update_dpp(                        \
             0, __float_as_int(pr), 0x141, 0xF, 0xF, true));                 \
    pr += __int_as_float(__builtin_amdgcn_update_dpp(                        \
             0, __float_as_int(pr), 0x140, 0xF, 0xF, true));                 \
    pr += __shfl_xor(pr, 16);                                                \
    const float outv = pr + b2v;                                             \
    pend_node = node0; pend_val = outv;                                      \
    /* 9: rotate */                                                          \
    node0 = node1; node1 = node2;                                            \
    bw0c = bw0n; bw1c = bw1n; vbn = vb2;                                     \
    w2v = w2v_n; b1v = b1v_n; xv = xv_n; b2v = b2v_n;                        \
    w1xv = w1xv_n; wfr = wfr_n;                                              \
    cnt4_c = cnt4n; nb_c = nbn;                                              \
  }

__global__ __launch_bounds__(64, 4) void cond_mlp(
    const float* __restrict__ x, const float* __restrict__ u,
    const float* __restrict__ W1, const float* __restrict__ b1,
    const float* __restrict__ W2, const float* __restrict__ b2,
    const int* __restrict__ order, const int* __restrict__ do_idxs,
    const ulonglong2* __restrict__ bitsT, float* __restrict__ out)
{
    const int b = blockIdx.x;
    const int lane = threadIdx.x;
    const int j = lane & 31;
    const int j4 = j << 2;
    const int half = lane >> 5;

    __shared__ float2 entb[2][132];

    const float ub = u[b];
    const int dob = __builtin_amdgcn_readfirstlane(do_idxs[b]);
    float out0 = (dob == lane) ? ub : 0.f;
    float out1 = (dob == lane + 64) ? ub : 0.f;

    unsigned long long nz0 = (dob >= 0 && dob < 64) ? (1ull << dob) : 0ull;
    unsigned long long nz1 = (dob >= 64) ? (1ull << (dob - 64)) : 0ull;

    const int* ord = order + b * NN;
    const ulonglong2* bb = bitsT + (size_t)b * NN;

    const unsigned long long lanebit = 1ull << lane;
    // W1 row BYTE offsets (d * HH * 4)
    const float fidx0 = __int_as_float(lane << 7);
    const float fidx1 = __int_as_float((lane + 64) << 7);

    // ---- prologue: set up step 0's entries + scalars ----
    int node0 = __builtin_amdgcn_readfirstlane(ord[0]);
    int node1 = __builtin_amdgcn_readfirstlane(ord[1]);
    const ulonglong2 vb0 = bb[node0];
    ulonglong2 vbn = bb[node1];

    unsigned long long bw0c = rfl64(vb0.x);
    unsigned long long bw1c = rfl64(vb0.y);
    int cnt4_c, nb_c;
    float2 eA[16], eB[16];
    {
        const unsigned long long m0 = nz0 & bw0c;
        const unsigned long long m1 = nz1 & bw1c;
        const int c0 = __popcll(m0);
        const int cnt = c0 + __popcll(m1);
        cnt4_c = (cnt + 3) & ~3;
        nb_c = (cnt >= 32) ? 4 : ((cnt + 7) >> 3);
        const int p0 = mbcnt64(m0);
        if (m0 & lanebit) entb[0][p0] = make_float2(out0, fidx0);
        const int p1 = c0 + mbcnt64(m1);
        if (m1 & lanebit) entb[0][p1] = make_float2(out1, fidx1);
        const int top = (nb_c * 8 > cnt4_c) ? nb_c * 8 : cnt4_c;
        const int pp = cnt + lane;
        if (pp < top) entb[0][pp] = make_float2(0.f, __int_as_float(0));
    }
    asm volatile("s_waitcnt lgkmcnt(0)" ::: "memory");
#pragma unroll
    for (int i = 0; i < 16; ++i) eA[i] = entb[0][2 * i + half];

    const float* Wn0 = W1 + (size_t)node0 * ((NN + 1) * HH);
    float w2v  = W2[node0 * HH + j];
    float b1v  = b1[node0 * HH + j];
    float xv   = x[b * NN + node0];
    float b2v  = b2[node0];
    float w1xv = Wn0[NN * HH + j];
    float wfr  = 0.f;

    int pend_node = 0;
    float pend_val = 0.f;

    // ---- main loop, unrolled by 2 to rotate register sets without moves ----
    for (int t = 0; t < NN; t += 2) {
        STEP(t,     eA, eB, 0, 1)
        STEP(t + 1, eB, eA, 1, 0)
    }

    // apply final pending update (from step NN-1)
    if (dob != pend_node && lane == (pend_node & 63)) {
        if (pend_node < 64) out0 = pend_val; else out1 = pend_val;
    }

    out[b * NN + lane] = out0;
    out[b * NN + 64 + lane] = out1;
}

extern "C" void kernel_launch(void* const* d_in, const int* in_sizes, int n_in,
                              void* d_out, int out_size, void* d_ws, size_t ws_size,
                              hipStream_t stream) {
    const float* x   = (const float*)d_in[0];
    const float* A   = (const float*)d_in[1];
    const float* u   = (const float*)d_in[2];
    const float* W1  = (const float*)d_in[3];
    const float* b1  = (const float*)d_in[4];
    const float* W2  = (const float*)d_in[5];
    const float* b2  = (const float*)d_in[6];
    const int* order = (const int*)d_in[7];
    const int* dox   = (const int*)d_in[8];

    ulonglong2* bitsT = (ulonglong2*)d_ws;  // 4096*128*16 B = 8 MB

    pack_bits<<<(BB * 32) / 256, 256, 0, stream>>>(A, bitsT);
    cond_mlp<<<BB, 64, 0, stream>>>(x, u, W1, b1, W2, b2, order, dox,
                                    bitsT, (float*)d_out);
}

// Round 7
// 527.135 us; speedup vs baseline: 2.0090x; 2.0090x over previous
//
#include <hip/hip_runtime.h>
#include <stdint.h>

#define NN 128
#define BB 4096
#define HH 32

typedef float f4 __attribute__((ext_vector_type(4)));

// Pre-pass: bit-pack A transposed. bit d of word (b,node) = (A[b][d][node] != 0).
__global__ __launch_bounds__(256) void pack_bits(const float* __restrict__ A,
                                                 ulonglong2* __restrict__ bitsT) {
    const int tid = blockIdx.x * 256 + threadIdx.x;   // BB*32 threads total
    const int b   = tid >> 5;
    const int ng  = (tid & 31) << 2;                  // this thread's 4 nodes
    const float* Ab = A + (size_t)b * (NN * NN) + ng;
    unsigned long long w0[4] = {0ull, 0ull, 0ull, 0ull};
    unsigned long long w1[4] = {0ull, 0ull, 0ull, 0ull};
#pragma unroll 8
    for (int d = 0; d < 64; ++d) {
        f4 v = __builtin_nontemporal_load((const f4*)(Ab + (size_t)d * NN));
        const unsigned long long bit = 1ull << d;
        if (v[0] != 0.f) w0[0] |= bit;
        if (v[1] != 0.f) w0[1] |= bit;
        if (v[2] != 0.f) w0[2] |= bit;
        if (v[3] != 0.f) w0[3] |= bit;
    }
#pragma unroll 8
    for (int d = 0; d < 64; ++d) {
        f4 v = __builtin_nontemporal_load((const f4*)(Ab + (size_t)(d + 64) * NN));
        const unsigned long long bit = 1ull << d;
        if (v[0] != 0.f) w1[0] |= bit;
        if (v[1] != 0.f) w1[1] |= bit;
        if (v[2] != 0.f) w1[2] |= bit;
        if (v[3] != 0.f) w1[3] |= bit;
    }
    ulonglong2* o = bitsT + b * NN + ng;
#pragma unroll
    for (int i = 0; i < 4; ++i) {
        ulonglong2 r; r.x = w0[i]; r.y = w1[i];
        o[i] = r;
    }
}

__device__ __forceinline__ int mbcnt64(unsigned long long m) {
    return __builtin_amdgcn_mbcnt_hi((unsigned int)(m >> 32),
           __builtin_amdgcn_mbcnt_lo((unsigned int)m, 0));
}
__device__ __forceinline__ unsigned long long rfl64(unsigned long long v) {
    unsigned int lo = __builtin_amdgcn_readfirstlane((unsigned int)v);
    unsigned int hi = __builtin_amdgcn_readfirstlane((unsigned int)(v >> 32));
    return ((unsigned long long)hi << 32) | lo;
}

// v8 = v6 pipeline (proven 184us) + issue cuts that respect the spill rule
// (r6 lesson: register arrays must be fully defined unconditionally; only
//  branch-LOCAL arrays may sit under SGPR-uniform branches):
//  (1) ent stores W1-row BYTE offsets (d<<7): W address = 1 v_add off SGPR base.
//  (2) no mid-step lgkmcnt(0): same-wave DS ops execute in order through the
//      LDS pipe, so the ds_reads following the compaction ds_writes see the
//      new data; lgkmcnt only guards VGPR results and the compiler inserts
//      that wait before first use (next step's W-address calc).
//  (3) ent deinterleaved by entry parity -> each half's 16 entries contiguous
//      -> 8 broadcast ds_read_b128 instead of 16 ds_read_b64.
//  (4) entries 32..47 as a static branch-local block (replaces the serial
//      dependent overflow loop on late steps); serial guard only cnt>48.
#define STEP(T, ECUR, ENXT, BCUR, BNXT)                                      \
  {                                                                          \
    const char* WnB = (const char*)(W1 + (size_t)node0 * ((NN + 1) * HH));   \
    /* 0: W loads for THIS step (byte offsets already in regs) */            \
    float wv[16];                                                            \
    _Pragma("unroll")                                                        \
    for (int q = 0; q < 8; ++q) {                                            \
        wv[2*q]   = *(const float*)(WnB + (__float_as_int(ECUR[q][1]) + j4));\
        wv[2*q+1] = *(const float*)(WnB + (__float_as_int(ECUR[q][3]) + j4));\
    }                                                                        \
    /* 1: apply pending update from step T-1 */                              \
    if ((T) > 0) {                                                           \
        if (dob != pend_node && lane == (pend_node & 63)) {                  \
            if (pend_node < 64) out0 = pend_val; else out1 = pend_val;       \
        }                                                                    \
        if (pend_node < 64) nz0 |= 1ull << pend_node;                        \
        else                nz1 |= 1ull << (pend_node - 64);                 \
    }                                                                        \
    /* 2: masks for step T+1 (node_T not yet in nz -> fresh path covers) */  \
    const unsigned long long bw0n = rfl64(vbn.x);                            \
    const unsigned long long bw1n = rfl64(vbn.y);                            \
    const unsigned long long m0 = nz0 & bw0n;                                \
    const unsigned long long m1 = nz1 & bw1n;                                \
    const int c0n  = __popcll(m0);                                           \
    const int cntn = c0n + __popcll(m1);                                     \
    /* 3: write compaction for T+1 (deinterleaved by entry parity) */        \
    {                                                                        \
        const int p0 = mbcnt64(m0);                                          \
        if (m0 & lanebit)                                                    \
            entb[BNXT][p0 & 1][p0 >> 1] = make_float2(out0, fidx0);          \
        const int p1 = c0n + mbcnt64(m1);                                    \
        if (m1 & lanebit)                                                    \
            entb[BNXT][p1 & 1][p1 >> 1] = make_float2(out1, fidx1);          \
        const int top = (cntn > 32) ? 48 : 32;                               \
        const int pp = cntn + lane;                                          \
        if (pp < top)                                                        \
            entb[BNXT][pp & 1][pp >> 1] = make_float2(0.f, __int_as_float(0));\
    }                                                                        \
    /* 4: entry reads for T+1 — b128 broadcast within each half (no wait:    \
          same-wave DS in-order; result-hazard wait auto-inserted next step) */\
    {                                                                        \
        const f4* eb = (const f4*)&entb[BNXT][half][0];                      \
        _Pragma("unroll")                                                    \
        for (int q = 0; q < 8; ++q) ENXT[q] = eb[q];                         \
    }                                                                        \
    /* 5: prefetch node_{T+2} bits + T+1 epilogue scalars */                 \
    const int node2 = ((T) + 2 < NN)                                         \
        ? __builtin_amdgcn_readfirstlane(ord[(T) + 2]) : 0;                  \
    const ulonglong2 vb2 = bb[node2];                                        \
    const float* Wn_nxt = W1 + (size_t)node1 * ((NN + 1) * HH);              \
    const float w2v_n  = W2[node1 * HH + j];                                 \
    const float b1v_n  = b1[node1 * HH + j];                                 \
    const float xv_n   = x[b * NN + node1];                                  \
    const float b2v_n  = b2[node1];                                          \
    const float w1xv_n = Wn_nxt[NN * HH + j];                                \
    const float wfr_n  = Wn_nxt[(node0 << 5) + j];                           \
    /* 6: FMAs for step T (entries + weights in regs) */                     \
    float a0 = 0.f, a1 = 0.f, a2 = 0.f, a3 = 0.f;                            \
    _Pragma("unroll")                                                        \
    for (int q = 0; q < 8; q += 2) {                                         \
        a0 += ECUR[q][0]     * wv[2*q];                                      \
        a1 += ECUR[q][2]     * wv[2*q+1];                                    \
        a2 += ECUR[q+1][0]   * wv[2*q+2];                                    \
        a3 += ECUR[q+1][2]   * wv[2*q+3];                                    \
    }                                                                        \
    /* 6b: entries 32..47 — branch-LOCAL fully-defined arrays (late steps) */\
    if (cnt_c > 32) {                                                        \
        f4 e3[4];                                                            \
        const f4* eb3 = (const f4*)&entb[BCUR][half][16];                    \
        _Pragma("unroll")                                                    \
        for (int q = 0; q < 4; ++q) e3[q] = eb3[q];                          \
        float w3[8];                                                         \
        _Pragma("unroll")                                                    \
        for (int q = 0; q < 4; ++q) {                                        \
            w3[2*q]   = *(const float*)(WnB + (__float_as_int(e3[q][1]) + j4));\
            w3[2*q+1] = *(const float*)(WnB + (__float_as_int(e3[q][3]) + j4));\
        }                                                                    \
        _Pragma("unroll")                                                    \
        for (int q = 0; q < 4; ++q) {                                        \
            a0 += e3[q][0] * w3[2*q];                                        \
            a1 += e3[q][2] * w3[2*q+1];                                      \
        }                                                                    \
        /* 6c: entries 48+ (rare statistical tail; correctness guard) */     \
        if (cnt_c > 48) {                                                    \
            for (int i = 24; 2 * i + half < cnt_c; ++i) {                    \
                float2 e = entb[BCUR][half][i];                              \
                a2 += e.x * *(const float*)(WnB + (__float_as_int(e.y) + j4));\
            }                                                                \
        }                                                                    \
    }                                                                        \
    float acc = (a0 + a1) + (a2 + a3);                                       \
    /* 8: finish step T */                                                   \
    float accT = acc + __shfl_xor(acc, 32);                                  \
    const bool fc = ((T) > 0) && (dob != pend_node) &&                       \
        ((((pend_node < 64) ? (bw0c >> pend_node)                            \
                            : (bw1c >> (pend_node - 64)))) & 1ull);          \
    accT += (fc ? pend_val : 0.f) * wfr;                                     \
    accT += xv * w1xv;                                                       \
    accT += b1v;                                                             \
    const float hv = (accT > 0.f) ? accT : 0.01f * accT;                     \
    float pr = hv * w2v;                                                     \
    pr += __int_as_float(__builtin_amdgcn_update_dpp(                        \
             0, __float_as_int(pr), 0xB1, 0xF, 0xF, true));                  \
    pr += __int_as_float(__builtin_amdgcn_update_dpp(                        \
             0, __float_as_int(pr), 0x4E, 0xF, 0xF, true));                  \
    pr += __int_as_float(__builtin_amdgcn_update_dpp(                        \
             0, __float_as_int(pr), 0x141, 0xF, 0xF, true));                 \
    pr += __int_as_float(__builtin_amdgcn_update_dpp(                        \
             0, __float_as_int(pr), 0x140, 0xF, 0xF, true));                 \
    pr += __shfl_xor(pr, 16);                                                \
    const float outv = pr + b2v;                                             \
    pend_node = node0; pend_val = outv;                                      \
    /* 9: rotate */                                                          \
    node0 = node1; node1 = node2;                                            \
    bw0c = bw0n; bw1c = bw1n; vbn = vb2;                                     \
    w2v = w2v_n; b1v = b1v_n; xv = xv_n; b2v = b2v_n;                        \
    w1xv = w1xv_n; wfr = wfr_n;                                              \
    cnt_c = cntn;                                                            \
  }

__global__ __launch_bounds__(64, 4) void cond_mlp(
    const float* __restrict__ x, const float* __restrict__ u,
    const float* __restrict__ W1, const float* __restrict__ b1,
    const float* __restrict__ W2, const float* __restrict__ b2,
    const int* __restrict__ order, const int* __restrict__ do_idxs,
    const ulonglong2* __restrict__ bitsT, float* __restrict__ out)
{
    const int b = blockIdx.x;
    const int lane = threadIdx.x;
    const int j = lane & 31;
    const int j4 = j << 2;
    const int half = lane >> 5;

    // [buf][entry parity][entry>>1]; inner row 68*8=544B (16B-aligned)
    __shared__ __align__(16) float2 entb[2][2][68];

    const float ub = u[b];
    const int dob = __builtin_amdgcn_readfirstlane(do_idxs[b]);
    float out0 = (dob == lane) ? ub : 0.f;
    float out1 = (dob == lane + 64) ? ub : 0.f;

    unsigned long long nz0 = (dob >= 0 && dob < 64) ? (1ull << dob) : 0ull;
    unsigned long long nz1 = (dob >= 64) ? (1ull << (dob - 64)) : 0ull;

    const int* ord = order + b * NN;
    const ulonglong2* bb = bitsT + (size_t)b * NN;

    const unsigned long long lanebit = 1ull << lane;
    // W1 row BYTE offsets (d * HH * 4 = d<<7)
    const float fidx0 = __int_as_float(lane << 7);
    const float fidx1 = __int_as_float((lane + 64) << 7);

    // ---- prologue: step 0's compaction + entries + scalars ----
    int node0 = __builtin_amdgcn_readfirstlane(ord[0]);
    int node1 = __builtin_amdgcn_readfirstlane(ord[1]);
    const ulonglong2 vb0 = bb[node0];
    ulonglong2 vbn = bb[node1];

    unsigned long long bw0c = rfl64(vb0.x);
    unsigned long long bw1c = rfl64(vb0.y);
    int cnt_c;
    f4 eA[8], eB[8];
    {
        const unsigned long long m0 = nz0 & bw0c;
        const unsigned long long m1 = nz1 & bw1c;
        const int c0 = __popcll(m0);
        cnt_c = c0 + __popcll(m1);
        const int p0 = mbcnt64(m0);
        if (m0 & lanebit) entb[0][p0 & 1][p0 >> 1] = make_float2(out0, fidx0);
        const int p1 = c0 + mbcnt64(m1);
        if (m1 & lanebit) entb[0][p1 & 1][p1 >> 1] = make_float2(out1, fidx1);
        const int top = (cnt_c > 32) ? 48 : 32;
        const int pp = cnt_c + lane;
        if (pp < top) entb[0][pp & 1][pp >> 1] = make_float2(0.f, __int_as_float(0));
        const f4* eb = (const f4*)&entb[0][half][0];
#pragma unroll
        for (int q = 0; q < 8; ++q) eA[q] = eb[q];
    }

    const float* Wn0 = W1 + (size_t)node0 * ((NN + 1) * HH);
    float w2v  = W2[node0 * HH + j];
    float b1v  = b1[node0 * HH + j];
    float xv   = x[b * NN + node0];
    float b2v  = b2[node0];
    float w1xv = Wn0[NN * HH + j];
    float wfr  = 0.f;

    int pend_node = 0;
    float pend_val = 0.f;

    // ---- main loop, unrolled by 2 to rotate register sets without moves ----
    for (int t = 0; t < NN; t += 2) {
        STEP(t,     eA, eB, 0, 1)
        STEP(t + 1, eB, eA, 1, 0)
    }

    // apply final pending update (from step NN-1)
    if (dob != pend_node && lane == (pend_node & 63)) {
        if (pend_node < 64) out0 = pend_val; else out1 = pend_val;
    }

    out[b * NN + lane] = out0;
    out[b * NN + 64 + lane] = out1;
}

extern "C" void kernel_launch(void* const* d_in, const int* in_sizes, int n_in,
                              void* d_out, int out_size, void* d_ws, size_t ws_size,
                              hipStream_t stream) {
    const float* x   = (const float*)d_in[0];
    const float* A   = (const float*)d_in[1];
    const float* u   = (const float*)d_in[2];
    const float* W1  = (const float*)d_in[3];
    const float* b1  = (const float*)d_in[4];
    const float* W2  = (const float*)d_in[5];
    const float* b2  = (const float*)d_in[6];
    const int* order = (const int*)d_in[7];
    const int* dox   = (const int*)d_in[8];

    ulonglong2* bitsT = (ulonglong2*)d_ws;  // 4096*128*16 B = 8 MB

    pack_bits<<<(BB * 32) / 256, 256, 0, stream>>>(A, bitsT);
    cond_mlp<<<BB, 64, 0, stream>>>(x, u, W1, b1, W2, b2, order, dox,
                                    bitsT, (float*)d_out);
}

// Round 8
// 516.563 us; speedup vs baseline: 2.0501x; 1.0205x over previous
//
#include <hip/hip_runtime.h>
#include <stdint.h>

#define NN 128
#define BB 4096
#define HH 32

typedef float f4 __attribute__((ext_vector_type(4)));

// Pre-pass: bit-pack A transposed. bit d of word (b,node) = (A[b][d][node] != 0).
// v9: d-quartered for occupancy — BB*128 threads (8192 waves = 8/SIMD, was 2).
// Each thread builds a 32-bit quarter-word for 4 nodes; the 4 quarter-threads
// of a node group write the 4 uint components of the ulonglong2 directly.
__global__ __launch_bounds__(256) void pack_bits(const float* __restrict__ A,
                                                 ulonglong2* __restrict__ bitsT) {
    const int tid = blockIdx.x * 256 + threadIdx.x;   // BB*128 threads total
    const int b  = tid >> 7;
    const int q  = (tid >> 5) & 3;        // which 32-row d-quarter
    const int ng = (tid & 31) << 2;       // this thread's 4 nodes
    const float* Ab = A + (size_t)b * (NN * NN) + (size_t)(q * 32) * NN + ng;
    unsigned int w[4] = {0u, 0u, 0u, 0u};
#pragma unroll 8
    for (int d = 0; d < 32; ++d) {
        f4 v = __builtin_nontemporal_load((const f4*)(Ab + (size_t)d * NN));
        const unsigned int bit = 1u << d;
        if (v[0] != 0.f) w[0] |= bit;
        if (v[1] != 0.f) w[1] |= bit;
        if (v[2] != 0.f) w[2] |= bit;
        if (v[3] != 0.f) w[3] |= bit;
    }
    // uint component q of bitsT[b*NN + ng + i] (little-endian: x = comp0|comp1<<32)
    unsigned int* o = (unsigned int*)(bitsT + (size_t)b * NN + ng);
#pragma unroll
    for (int i = 0; i < 4; ++i) o[i * 4 + q] = w[i];
}

__device__ __forceinline__ int mbcnt64(unsigned long long m) {
    return __builtin_amdgcn_mbcnt_hi((unsigned int)(m >> 32),
           __builtin_amdgcn_mbcnt_lo((unsigned int)m, 0));
}
__device__ __forceinline__ unsigned long long rfl64(unsigned long long v) {
    unsigned int lo = __builtin_amdgcn_readfirstlane((unsigned int)v);
    unsigned int hi = __builtin_amdgcn_readfirstlane((unsigned int)(v >> 32));
    return ((unsigned long long)hi << 32) | lo;
}

// Rotating per-step pipeline state. Double-buffered (SA/SB alternate as
// cur/next with the unroll-2) so the phase-9 rotation of r7 (~10 movs/step)
// becomes pure register renaming. All accesses constant-indexed -> registers.
struct Pipe {
    int node;                       // node of this step (when used as cur)
    int cnt;                        // entry count for this step
    unsigned long long bw0, bw1;    // bit words of this node
    ulonglong2 vb;                  // raw bits vector prefetch (next-next node)
    float w2v, b1v, xv, b2v, w1xv, wfr;
};

// v9 cond_mlp = r7 (validated 180us) with struct double-buffered scalars.
// Schedule per step T (SC = state for T, SN = state for T+1):
//  0: W loads for T from register-resident byte offsets (ECUR)
//  1: apply pending update from T-1; add node_{T-1} to nz
//  2: masks for T+1 from SN.vb -> SN.bw*/SN.cnt
//  3: compaction writes for T+1 into entb[BNXT] (values current through T-1;
//     node_T excluded -> covered by the fresh path at T+1)
//  4: entry ds_reads for T+1 -> ENXT (no lgkmcnt: same-wave DS is in-order,
//     result-hazard wait auto-inserted before first use next step)
//  5: prefetch node_{T+2} bits -> SC.{node,vb}; T+1 epilogue scalars -> SN
//  6: FMAs for T; 6b/6c overflow blocks (branch-local arrays only)
//  8: merge + fresh term + leaky_relu + DPP reduction -> outv -> pend
#define STEP(T, ECUR, ENXT, SC, SN, BCUR, BNXT)                              \
  {                                                                          \
    const int nodeT = SC.node;                                               \
    const char* WnB = (const char*)(W1 + (size_t)nodeT * ((NN + 1) * HH));   \
    /* 0 */                                                                  \
    float wv[16];                                                            \
    _Pragma("unroll")                                                        \
    for (int q = 0; q < 8; ++q) {                                            \
        wv[2*q]   = *(const float*)(WnB + (__float_as_int(ECUR[q][1]) + j4));\
        wv[2*q+1] = *(const float*)(WnB + (__float_as_int(ECUR[q][3]) + j4));\
    }                                                                        \
    /* 1 */                                                                  \
    if ((T) > 0) {                                                           \
        if (dob != pend_node && lane == (pend_node & 63)) {                  \
            if (pend_node < 64) out0 = pend_val; else out1 = pend_val;       \
        }                                                                    \
        if (pend_node < 64) nz0 |= 1ull << pend_node;                        \
        else                nz1 |= 1ull << (pend_node - 64);                 \
    }                                                                        \
    /* 2 */                                                                  \
    const unsigned long long bw0n = rfl64(SN.vb.x);                          \
    const unsigned long long bw1n = rfl64(SN.vb.y);                          \
    const unsigned long long m0 = nz0 & bw0n;                                \
    const unsigned long long m1 = nz1 & bw1n;                                \
    const int c0n  = __popcll(m0);                                           \
    const int cntn = c0n + __popcll(m1);                                     \
    SN.bw0 = bw0n; SN.bw1 = bw1n; SN.cnt = cntn;                             \
    /* 3 */                                                                  \
    {                                                                        \
        const int p0 = mbcnt64(m0);                                          \
        if (m0 & lanebit)                                                    \
            entb[BNXT][p0 & 1][p0 >> 1] = make_float2(out0, fidx0);          \
        const int p1 = c0n + mbcnt64(m1);                                    \
        if (m1 & lanebit)                                                    \
            entb[BNXT][p1 & 1][p1 >> 1] = make_float2(out1, fidx1);          \
        const int top = (cntn > 32) ? 48 : 32;                               \
        const int pp = cntn + lane;                                          \
        if (pp < top)                                                        \
            entb[BNXT][pp & 1][pp >> 1] = make_float2(0.f, __int_as_float(0));\
    }                                                                        \
    /* 4 */                                                                  \
    {                                                                        \
        const f4* eb = (const f4*)&entb[BNXT][half][0];                      \
        _Pragma("unroll")                                                    \
        for (int q = 0; q < 8; ++q) ENXT[q] = eb[q];                         \
    }                                                                        \
    /* 5 */                                                                  \
    const int node2 = ((T) + 2 < NN)                                         \
        ? __builtin_amdgcn_readfirstlane(ord[(T) + 2]) : 0;                  \
    SC.node = node2;                                                         \
    SC.vb   = bb[node2];                                                     \
    {                                                                        \
        const float* Wn_nxt = W1 + (size_t)SN.node * ((NN + 1) * HH);        \
        SN.w2v  = W2[SN.node * HH + j];                                      \
        SN.b1v  = b1[SN.node * HH + j];                                      \
        SN.xv   = x[b * NN + SN.node];                                       \
        SN.b2v  = b2[SN.node];                                               \
        SN.w1xv = Wn_nxt[NN * HH + j];                                       \
        SN.wfr  = Wn_nxt[(nodeT << 5) + j];                                  \
    }                                                                        \
    /* 6 */                                                                  \
    float a0 = 0.f, a1 = 0.f, a2 = 0.f, a3 = 0.f;                            \
    _Pragma("unroll")                                                        \
    for (int q = 0; q < 8; q += 2) {                                         \
        a0 += ECUR[q][0]     * wv[2*q];                                      \
        a1 += ECUR[q][2]     * wv[2*q+1];                                    \
        a2 += ECUR[q+1][0]   * wv[2*q+2];                                    \
        a3 += ECUR[q+1][2]   * wv[2*q+3];                                    \
    }                                                                        \
    /* 6b: entries 32..47 — branch-LOCAL fully-defined arrays */             \
    if (SC_cnt_snap > 32) {                                                  \
        f4 e3[4];                                                            \
        const f4* eb3 = (const f4*)&entb[BCUR][half][16];                    \
        _Pragma("unroll")                                                    \
        for (int q = 0; q < 4; ++q) e3[q] = eb3[q];                          \
        float w3[8];                                                         \
        _Pragma("unroll")                                                    \
        for (int q = 0; q < 4; ++q) {                                        \
            w3[2*q]   = *(const float*)(WnB + (__float_as_int(e3[q][1]) + j4));\
            w3[2*q+1] = *(const float*)(WnB + (__float_as_int(e3[q][3]) + j4));\
        }                                                                    \
        _Pragma("unroll")                                                    \
        for (int q = 0; q < 4; ++q) {                                        \
            a0 += e3[q][0] * w3[2*q];                                        \
            a1 += e3[q][2] * w3[2*q+1];                                      \
        }                                                                    \
        /* 6c: entries 48+ (rare statistical tail; correctness guard) */     \
        if (SC_cnt_snap > 48) {                                              \
            for (int i = 24; 2 * i + half < SC_cnt_snap; ++i) {              \
                float2 e = entb[BCUR][half][i];                              \
                a2 += e.x * *(const float*)(WnB + (__float_as_int(e.y) + j4));\
            }                                                                \
        }                                                                    \
    }                                                                        \
    float acc = (a0 + a1) + (a2 + a3);                                       \
    /* 8 */                                                                  \
    float accT = acc + __shfl_xor(acc, 32);                                  \
    const bool fc = ((T) > 0) && (dob != pend_node) &&                       \
        ((((pend_node < 64) ? (SC.bw0 >> pend_node)                          \
                            : (SC.bw1 >> (pend_node - 64)))) & 1ull);        \
    accT += (fc ? pend_val : 0.f) * SC.wfr;                                  \
    accT += SC.xv * SC.w1xv;                                                 \
    accT += SC.b1v;                                                          \
    const float hv = (accT > 0.f) ? accT : 0.01f * accT;                     \
    float pr = hv * SC.w2v;                                                  \
    pr += __int_as_float(__builtin_amdgcn_update_dpp(                        \
             0, __float_as_int(pr), 0xB1, 0xF, 0xF, true));                  \
    pr += __int_as_float(__builtin_amdgcn_update_dpp(                        \
             0, __float_as_int(pr), 0x4E, 0xF, 0xF, true));                  \
    pr += __int_as_float(__builtin_amdgcn_update_dpp(                        \
             0, __float_as_int(pr), 0x141, 0xF, 0xF, true));                 \
    pr += __int_as_float(__builtin_amdgcn_update_dpp(                        \
             0, __float_as_int(pr), 0x140, 0xF, 0xF, true));                 \
    pr += __shfl_xor(pr, 16);                                                \
    const float outv = pr + SC.b2v;                                          \
    pend_node = nodeT; pend_val = outv;                                      \
  }

__global__ __launch_bounds__(64, 4) void cond_mlp(
    const float* __restrict__ x, const float* __restrict__ u,
    const float* __restrict__ W1, const float* __restrict__ b1,
    const float* __restrict__ W2, const float* __restrict__ b2,
    const int* __restrict__ order, const int* __restrict__ do_idxs,
    const ulonglong2* __restrict__ bitsT, float* __restrict__ out)
{
    const int b = blockIdx.x;
    const int lane = threadIdx.x;
    const int j = lane & 31;
    const int j4 = j << 2;
    const int half = lane >> 5;

    // [buf][entry parity][entry>>1]; inner row 68*8=544B (16B-aligned)
    __shared__ __align__(16) float2 entb[2][2][68];

    const float ub = u[b];
    const int dob = __builtin_amdgcn_readfirstlane(do_idxs[b]);
    float out0 = (dob == lane) ? ub : 0.f;
    float out1 = (dob == lane + 64) ? ub : 0.f;

    unsigned long long nz0 = (dob >= 0 && dob < 64) ? (1ull << dob) : 0ull;
    unsigned long long nz1 = (dob >= 64) ? (1ull << (dob - 64)) : 0ull;

    const int* ord = order + b * NN;
    const ulonglong2* bb = bitsT + (size_t)b * NN;

    const unsigned long long lanebit = 1ull << lane;
    // W1 row BYTE offsets (d * HH * 4 = d<<7)
    const float fidx0 = __int_as_float(lane << 7);
    const float fidx1 = __int_as_float((lane + 64) << 7);

    // ---- prologue: fill SA (step 0) and SB (step 1 prefetch) ----
    Pipe SA, SB;
    SA.node = __builtin_amdgcn_readfirstlane(ord[0]);
    SB.node = __builtin_amdgcn_readfirstlane(ord[1]);
    SB.vb = bb[SB.node];
    SA.vb = bb[SA.node];   // consumed immediately below for step 0's masks

    SA.bw0 = rfl64(SA.vb.x);
    SA.bw1 = rfl64(SA.vb.y);
    f4 eA[8], eB[8];
    {
        const unsigned long long m0 = nz0 & SA.bw0;
        const unsigned long long m1 = nz1 & SA.bw1;
        const int c0 = __popcll(m0);
        SA.cnt = c0 + __popcll(m1);
        const int p0 = mbcnt64(m0);
        if (m0 & lanebit) entb[0][p0 & 1][p0 >> 1] = make_float2(out0, fidx0);
        const int p1 = c0 + mbcnt64(m1);
        if (m1 & lanebit) entb[0][p1 & 1][p1 >> 1] = make_float2(out1, fidx1);
        const int top = (SA.cnt > 32) ? 48 : 32;
        const int pp = SA.cnt + lane;
        if (pp < top) entb[0][pp & 1][pp >> 1] = make_float2(0.f, __int_as_float(0));
        const f4* eb = (const f4*)&entb[0][half][0];
#pragma unroll
        for (int q = 0; q < 8; ++q) eA[q] = eb[q];
    }
    {
        const float* Wn0 = W1 + (size_t)SA.node * ((NN + 1) * HH);
        SA.w2v  = W2[SA.node * HH + j];
        SA.b1v  = b1[SA.node * HH + j];
        SA.xv   = x[b * NN + SA.node];
        SA.b2v  = b2[SA.node];
        SA.w1xv = Wn0[NN * HH + j];
        SA.wfr  = 0.f;
    }

    int pend_node = 0;
    float pend_val = 0.f;

    // ---- main loop: unroll-2 alternates (eA,SA,buf0) / (eB,SB,buf1) ----
    for (int t = 0; t < NN; t += 2) {
        const int SC_cnt_snap0 = SA.cnt;
        { const int SC_cnt_snap = SC_cnt_snap0;
          STEP(t,     eA, eB, SA, SB, 0, 1) }
        const int SC_cnt_snap1 = SB.cnt;
        { const int SC_cnt_snap = SC_cnt_snap1;
          STEP(t + 1, eB, eA, SB, SA, 1, 0) }
    }

    // apply final pending update (from step NN-1)
    if (dob != pend_node && lane == (pend_node & 63)) {
        if (pend_node < 64) out0 = pend_val; else out1 = pend_val;
    }

    out[b * NN + lane] = out0;
    out[b * NN + 64 + lane] = out1;
}

extern "C" void kernel_launch(void* const* d_in, const int* in_sizes, int n_in,
                              void* d_out, int out_size, void* d_ws, size_t ws_size,
                              hipStream_t stream) {
    const float* x   = (const float*)d_in[0];
    const float* A   = (const float*)d_in[1];
    const float* u   = (const float*)d_in[2];
    const float* W1  = (const float*)d_in[3];
    const float* b1  = (const float*)d_in[4];
    const float* W2  = (const float*)d_in[5];
    const float* b2  = (const float*)d_in[6];
    const int* order = (const int*)d_in[7];
    const int* dox   = (const int*)d_in[8];

    ulonglong2* bitsT = (ulonglong2*)d_ws;  // 4096*128*16 B = 8 MB

    pack_bits<<<(BB * 128) / 256, 256, 0, stream>>>(A, bitsT);
    cond_mlp<<<BB, 64, 0, stream>>>(x, u, W1, b1, W2, b2, order, dox,
                                    bitsT, (float*)d_out);
}